// Round 13
// baseline (183.366 us; speedup 1.0000x reference)
//
#include <hip/hip_runtime.h>
#include <hip/hip_bf16.h>

// MHA forward: B=4, S=1024, D=1024, H=16, DK=64
// outputs: out [4,1024,1024] f32, attn [4,16,1024,1024] f32 (concat in d_out)
//
// Packed operand layouts for the fused kernel (all bf16):
//   qhp/khp: [bh][half=dk/32][s][32]   -> frag loads 1KB contiguous
//   vp:      [bh][kb=s/32][dk][32]     -> PV frag loads 1KB contiguous

typedef __bf16 bf16_t;
typedef __bf16 bf16x4 __attribute__((ext_vector_type(4)));
typedef __bf16 bf16x8 __attribute__((ext_vector_type(8)));
typedef float f32x4 __attribute__((ext_vector_type(4)));

#define MFMA16(a, b, c) __builtin_amdgcn_mfma_f32_16x16x32_bf16(a, b, c, 0, 0, 0)

// async global->LDS, 16B per lane; LDS dest = uniform base + lane*16 (linear)
#define GLOAD16(g, l)                                                        \
    __builtin_amdgcn_global_load_lds(                                        \
        (const __attribute__((address_space(1))) unsigned int*)(g),          \
        (__attribute__((address_space(3))) unsigned int*)(l), 16, 0, 0)

// ---------------------------------------------------------------- cast x -> bf16
__global__ __launch_bounds__(256) void cast_f32_bf16(const float* __restrict__ in,
                                                     bf16_t* __restrict__ out, int n4) {
    int i = blockIdx.x * blockDim.x + threadIdx.x;
    if (i >= n4) return;
    float4 v = reinterpret_cast<const float4*>(in)[i];
    bf16x4 o = { (bf16_t)v.x, (bf16_t)v.y, (bf16_t)v.z, (bf16_t)v.w };
    reinterpret_cast<bf16x4*>(out)[i] = o;
}

// ------------------------------------------- transpose + cast the 4 weight matrices
__global__ __launch_bounds__(1024) void transpose_cast_w(const float* __restrict__ w0,
                                                         const float* __restrict__ w1,
                                                         const float* __restrict__ w2,
                                                         const float* __restrict__ w3,
                                                         bf16_t* __restrict__ wt) {
    __shared__ float tile[32][33];
    const float* src = (blockIdx.z == 0) ? w0 : (blockIdx.z == 1) ? w1
                     : (blockIdx.z == 2) ? w2 : w3;
    bf16_t* dst = wt + (size_t)blockIdx.z * 1024 * 1024;
    int r0 = blockIdx.y * 32, c0 = blockIdx.x * 32;
    tile[threadIdx.y][threadIdx.x] = src[(size_t)(r0 + threadIdx.y) * 1024 + c0 + threadIdx.x];
    __syncthreads();
    dst[(size_t)(c0 + threadIdx.y) * 1024 + r0 + threadIdx.x] = (bf16_t)tile[threadIdx.x][threadIdx.y];
}

// --------------------------------- GEMM core (128x128 tile, BK=32, m97 structure)
// Double-buffered LDS + global_load_lds(16B): loads for tile t+1 issued right
// after the barrier, in flight during compute of tile t, drained by the next
// barrier's vmcnt. Rule #21 discipline: LDS dest LINEAR (chunk base + lane*16);
// global source pre-swizzled (lane l, chunk c: row r = c*16 + (l>>2), slot
// s = (l&3) ^ ((r>>1)&3)) so position p of row r holds slot p ^ ((r>>1)&3) —
// matching the read side's lg ^ ((row>>1)&3) (2-way aliasing = free, m136).
// One barrier per K-step; wave w stages chunks {w, w+4} of A and B.
#define GEMM_BODY(A, BT)                                                                 \
    __shared__ bf16_t As[2][128 * 32];                                                   \
    __shared__ bf16_t Bs[2][128 * 32];                                                   \
    const int tid = threadIdx.x;                                                         \
    const int lane = tid & 63, wave = tid >> 6;                                          \
    const int lr = lane & 15, lg = lane >> 4;                                            \
    const int m_base = blockIdx.x * 128, n_base = blockIdx.y * 128;                      \
    const int wm = (wave >> 1) * 64, wn = (wave & 1) * 64;                               \
    const int c0_ = wave, c1_ = wave + 4;                                                \
    const int r0_ = c0_ * 16 + (lane >> 2);                                              \
    const int r1_ = c1_ * 16 + (lane >> 2);                                              \
    const int s0_ = (lane & 3) ^ ((r0_ >> 1) & 3);                                       \
    const int s1_ = (lane & 3) ^ ((r1_ >> 1) & 3);                                       \
    const bf16_t* ga0_ = (A) + (size_t)(m_base + r0_) * 1024 + s0_ * 8;                  \
    const bf16_t* ga1_ = (A) + (size_t)(m_base + r1_) * 1024 + s1_ * 8;                  \
    const bf16_t* gb0_ = (BT) + (size_t)(n_base + r0_) * 1024 + s0_ * 8;                 \
    const bf16_t* gb1_ = (BT) + (size_t)(n_base + r1_) * 1024 + s1_ * 8;                 \
    f32x4 acc[4][4] = {};                                                                \
    GLOAD16(ga0_, &As[0][c0_ * 512]);                                                    \
    GLOAD16(ga1_, &As[0][c1_ * 512]);                                                    \
    GLOAD16(gb0_, &Bs[0][c0_ * 512]);                                                    \
    GLOAD16(gb1_, &Bs[0][c1_ * 512]);                                                    \
    int cur_ = 0;                                                                        \
    for (int t = 0; t < 32; ++t) {                                                       \
        __syncthreads();          /* vmcnt drained -> buf[cur_] ready */                 \
        if (t < 31) {                                                                    \
            const int kb = (t + 1) * 32;                                                 \
            GLOAD16(ga0_ + kb, &As[cur_ ^ 1][c0_ * 512]);                                \
            GLOAD16(ga1_ + kb, &As[cur_ ^ 1][c1_ * 512]);                                \
            GLOAD16(gb0_ + kb, &Bs[cur_ ^ 1][c0_ * 512]);                                \
            GLOAD16(gb1_ + kb, &Bs[cur_ ^ 1][c1_ * 512]);                                \
        }                                                                                \
        bf16x8 af[4], bfr[4];                                                            \
        _Pragma("unroll") for (int i = 0; i < 4; ++i) {                                  \
            const int row = wm + i * 16 + lr;                                            \
            af[i] = *reinterpret_cast<const bf16x8*>(                                    \
                &As[cur_][row * 32 + ((lg ^ ((row >> 1) & 3)) * 8)]);                    \
        }                                                                                \
        _Pragma("unroll") for (int j = 0; j < 4; ++j) {                                  \
            const int row = wn + j * 16 + lr;                                            \
            bfr[j] = *reinterpret_cast<const bf16x8*>(                                   \
                &Bs[cur_][row * 32 + ((lg ^ ((row >> 1) & 3)) * 8)]);                    \
        }                                                                                \
        _Pragma("unroll") for (int i = 0; i < 4; ++i)                                    \
            _Pragma("unroll") for (int j = 0; j < 4; ++j)                                \
                acc[i][j] = MFMA16(af[i], bfr[j], acc[i][j]);                            \
        cur_ ^= 1;                                                                       \
    }

// ---------------------------------------------------- QKV projections, one launch
// blockIdx.z: 0 = Q -> qhp (x0.125), 1 = K -> khp, 2 = V -> vp
__global__ __launch_bounds__(256, 3) void gemm_qkv(const bf16_t* __restrict__ A,
                                                   const bf16_t* __restrict__ wT,
                                                   bf16_t* __restrict__ qhp,
                                                   bf16_t* __restrict__ khp,
                                                   bf16_t* __restrict__ vp) {
    const int z = blockIdx.z;
    const bf16_t* BT = wT + ((size_t)z << 20);
    GEMM_BODY(A, BT)
    bf16_t* dst = (z == 0) ? qhp : (z == 1) ? khp : vp;
    const float scale = (z == 0) ? 0.125f : 1.0f;
#pragma unroll
    for (int i = 0; i < 4; ++i)
#pragma unroll
        for (int j = 0; j < 4; ++j)
#pragma unroll
            for (int r = 0; r < 4; ++r) {
                const int row = m_base + wm + i * 16 + lg * 4 + r;
                const int col = n_base + wn + j * 16 + lr;
                const float v = acc[i][j][r] * scale;
                const int b = row >> 10, s = row & 1023;
                const int h = col >> 6, d = col & 63;
                const size_t bh16 = (size_t)(b * 16 + h) << 16;
                if (z == 2)   // vp[bh][s/32][d][s%32]
                    dst[bh16 + ((s >> 5) << 11) + d * 32 + (s & 31)] = (bf16_t)v;
                else          // qhp/khp[bh][d/32][s][d%32]
                    dst[bh16 + ((d >> 5) << 15) + s * 32 + (d & 31)] = (bf16_t)v;
            }
}

// ------------------------------------------------------------- output projection
__global__ __launch_bounds__(256, 3) void gemm_out(const bf16_t* __restrict__ A,
                                                   const bf16_t* __restrict__ BT,
                                                   float* __restrict__ out) {
    GEMM_BODY(A, BT)
#pragma unroll
    for (int i = 0; i < 4; ++i)
#pragma unroll
        for (int j = 0; j < 4; ++j)
#pragma unroll
            for (int r = 0; r < 4; ++r) {
                const int row = m_base + wm + i * 16 + lg * 4 + r;
                const int col = n_base + wn + j * 16 + lr;
                out[(size_t)row * 1024 + col] = acc[i][j][r];
            }
}

// --------------------------------------- fused scores+bias+softmax+attn-write+PV
// (unchanged from round 11 — 2-q-tile, K/V loaded once, segment-coalesced I/O)
__global__ __launch_bounds__(256, 2) void fused_attn(const bf16_t* __restrict__ qhp,
                                                     const bf16_t* __restrict__ khp,
                                                     const bf16_t* __restrict__ vp,
                                                     const float* __restrict__ bias,
                                                     float* __restrict__ attn,
                                                     bf16_t* __restrict__ ctxb) {
    __shared__ f32x4 wlds4[4][1024];        // 65536 B: per-wave 16KB region
    __shared__ float smaxp[128];            // [tile][wave*16+q]
    __shared__ float ssump[128];
    const int lane = threadIdx.x & 63;
    const int wave = threadIdx.x >> 6;
    const int lr = lane & 15, lg = lane >> 4;

    // decode 2048 blocks: g&7 = xcd slot; per-xcd: b fastest, qt, then h-ext
    const int g = blockIdx.x;
    const int j = g >> 3;                   // 0..255
    const int h = (g & 7) + 8 * (j >> 7);   // 0..15
    const int qt = (j >> 2) & 31;           // 32-row q-tile
    const int b = j & 3;
    const int bh = b * 16 + h;
    const int m0 = qt * 32;                 // tile0: m0..+15, tile1: m0+16..+31

    // Q B-frags for both tiles
    const bf16_t* qbase = qhp + ((size_t)bh << 16);
    const bf16x8 aqA0 = *reinterpret_cast<const bf16x8*>(qbase + (m0 + lr) * 32 + lg * 8);
    const bf16x8 aqA1 = *reinterpret_cast<const bf16x8*>(qbase + 32768 + (m0 + lr) * 32 + lg * 8);
    const bf16x8 aqB0 = *reinterpret_cast<const bf16x8*>(qbase + (m0 + 16 + lr) * 32 + lg * 8);
    const bf16x8 aqB1 = *reinterpret_cast<const bf16x8*>(qbase + 32768 + (m0 + 16 + lr) * 32 + lg * 8);

    const int c0 = wave * 256;              // this wave's k-col slice
    const bf16_t* kp0 = khp + ((size_t)bh << 16) + (size_t)(c0 + lr) * 32 + lg * 8;

    char* tw = reinterpret_cast<char*>(&wlds4[wave][0]);
    const int myswz = (lr & 7) << 4;

    // ---- bias tile0 -> LDS (permuted global col, linear LDS dest = swizzled tile)
    const float* bb0 = bias + ((size_t)h << 20) + (size_t)m0 * 1024 + c0;
#pragma unroll
    for (int i = 0; i < 16; ++i) {
        const int co = (lane * 4) ^ ((i & 7) * 4);
        f32x4 bv = *reinterpret_cast<const f32x4*>(bb0 + (size_t)i * 1024 + co);
        *reinterpret_cast<f32x4*>(tw + i * 1024 + lane * 16) = bv;
    }
    f32x4 acc0[16];
#pragma unroll
    for (int f = 0; f < 16; ++f)
        acc0[f] = *reinterpret_cast<const f32x4*>(tw + lr * 1024 + ((f * 64 + lg * 16) ^ myswz));

    // ---- bias tile1 -> LDS (reuse region), init acc1
    const float* bb1 = bb0 + 16 * 1024;
#pragma unroll
    for (int i = 0; i < 16; ++i) {
        const int co = (lane * 4) ^ ((i & 7) * 4);
        f32x4 bv = *reinterpret_cast<const f32x4*>(bb1 + (size_t)i * 1024 + co);
        *reinterpret_cast<f32x4*>(tw + i * 1024 + lane * 16) = bv;
    }
    f32x4 acc1[16];
#pragma unroll
    for (int f = 0; f < 16; ++f)
        acc1[f] = *reinterpret_cast<const f32x4*>(tw + lr * 1024 + ((f * 64 + lg * 16) ^ myswz));

    // ---- QK^T (swapped) for both tiles; K in 4 transient batches of 8 frags
#pragma unroll
    for (int half = 0; half < 2; ++half) {
        const bf16x8 aqA = half ? aqA1 : aqA0;
        const bf16x8 aqB = half ? aqB1 : aqB0;
#pragma unroll
        for (int bt = 0; bt < 2; ++bt) {
            bf16x8 kf[8];
#pragma unroll
            for (int u = 0; u < 8; ++u)
                kf[u] = *reinterpret_cast<const bf16x8*>(
                    kp0 + half * 32768 + (bt * 8 + u) * 512);
#pragma unroll
            for (int u = 0; u < 8; ++u) {
                acc0[bt * 8 + u] = MFMA16(kf[u], aqA, acc0[bt * 8 + u]);
                acc1[bt * 8 + u] = MFMA16(kf[u], aqB, acc1[bt * 8 + u]);
            }
        }
    }

    // ---- row max (both tiles): in-lane over 64 + shuffle xor16/32 + LDS
    f32x4 m40 = acc0[0], m41 = acc1[0];
#pragma unroll
    for (int f = 1; f < 16; ++f) {
#pragma unroll
        for (int r = 0; r < 4; ++r) {
            m40[r] = fmaxf(m40[r], acc0[f][r]);
            m41[r] = fmaxf(m41[r], acc1[f][r]);
        }
    }
    float mx0 = fmaxf(fmaxf(m40[0], m40[1]), fmaxf(m40[2], m40[3]));
    float mx1 = fmaxf(fmaxf(m41[0], m41[1]), fmaxf(m41[2], m41[3]));
    mx0 = fmaxf(mx0, __shfl_xor(mx0, 16));
    mx0 = fmaxf(mx0, __shfl_xor(mx0, 32));
    mx1 = fmaxf(mx1, __shfl_xor(mx1, 16));
    mx1 = fmaxf(mx1, __shfl_xor(mx1, 32));
    if (lane < 16) {
        smaxp[wave * 16 + lr] = mx0;
        smaxp[64 + wave * 16 + lr] = mx1;
    }
    __syncthreads();
    const float gm0 = fmaxf(fmaxf(smaxp[lr], smaxp[16 + lr]),
                            fmaxf(smaxp[32 + lr], smaxp[48 + lr]));
    const float gm1 = fmaxf(fmaxf(smaxp[64 + lr], smaxp[80 + lr]),
                            fmaxf(smaxp[96 + lr], smaxp[112 + lr]));

    // ---- exp once + row sums (both tiles)
    f32x4 s40 = {0.f, 0.f, 0.f, 0.f}, s41 = {0.f, 0.f, 0.f, 0.f};
#pragma unroll
    for (int f = 0; f < 16; ++f) {
#pragma unroll
        for (int r = 0; r < 4; ++r) {
            const float e0 = __expf(acc0[f][r] - gm0);
            const float e1 = __expf(acc1[f][r] - gm1);
            acc0[f][r] = e0;
            acc1[f][r] = e1;
            s40[r] += e0;
            s41[r] += e1;
        }
    }
    float sm0 = (s40[0] + s40[1]) + (s40[2] + s40[3]);
    float sm1 = (s41[0] + s41[1]) + (s41[2] + s41[3]);
    sm0 += __shfl_xor(sm0, 16);
    sm0 += __shfl_xor(sm0, 32);
    sm1 += __shfl_xor(sm1, 16);
    sm1 += __shfl_xor(sm1, 32);
    if (lane < 16) {
        ssump[wave * 16 + lr] = sm0;
        ssump[64 + wave * 16 + lr] = sm1;
    }
    __syncthreads();
    const float invl0 = 1.0f / (ssump[lr] + ssump[16 + lr] + ssump[32 + lr] + ssump[48 + lr]);
    const float invl1 = 1.0f / (ssump[64 + lr] + ssump[80 + lr] + ssump[96 + lr] + ssump[112 + lr]);

    // ---- issue V batch 0 early (shared by both tiles' PV)
    const bf16_t* vpb = vp + ((size_t)bh << 16) + (size_t)(wave * 8) * 2048 + lr * 32 + lg * 8;
    bf16x8 vf0[4][4];
#pragma unroll
    for (int ks = 0; ks < 4; ++ks)
#pragma unroll
        for (int f2 = 0; f2 < 4; ++f2)
            vf0[ks][f2] = *reinterpret_cast<const bf16x8*>(vpb + ks * 2048 + f2 * 512);

    // ---- normalize -> P tiles (bf16, frag-order swizzled): P0 @ 0, P1 @ 8192
#pragma unroll
    for (int f = 0; f < 16; ++f) {
        f32x4 v0 = acc0[f], v1 = acc1[f];
#pragma unroll
        for (int r = 0; r < 4; ++r) { v0[r] *= invl0; v1[r] *= invl1; }
        bf16x4 p0 = { (bf16_t)v0[0], (bf16_t)v0[1], (bf16_t)v0[2], (bf16_t)v0[3] };
        bf16x4 p1 = { (bf16_t)v1[0], (bf16_t)v1[1], (bf16_t)v1[2], (bf16_t)v1[3] };
        const int ro = lr * 512 + ((f * 32 + lg * 8) ^ myswz);
        *reinterpret_cast<bf16x4*>(tw + ro) = p0;
        *reinterpret_cast<bf16x4*>(tw + 8192 + ro) = p1;
    }

    // ---- attn stores from P tiles: linear LDS b64 read -> cvt f32 -> permuted
    //      global col cc = (lane*4)^((i&7)*8); footprint 1KB contiguous per instr
    {
        float* obase = attn + ((size_t)bh << 20) + (size_t)m0 * 1024 + c0;
#pragma unroll
        for (int i = 0; i < 16; ++i) {
            const int cc = (lane * 4) ^ ((i & 7) * 8);
            bf16x4 q0 = *reinterpret_cast<const bf16x4*>(tw + i * 512 + lane * 8);
            bf16x4 q1 = *reinterpret_cast<const bf16x4*>(tw + 8192 + i * 512 + lane * 8);
            f32x4 w0 = { (float)q0[0], (float)q0[1], (float)q0[2], (float)q0[3] };
            f32x4 w1 = { (float)q1[0], (float)q1[1], (float)q1[2], (float)q1[3] };
            *reinterpret_cast<f32x4*>(obase + (size_t)i * 1024 + cc) = w0;
            *reinterpret_cast<f32x4*>(obase + (size_t)(16 + i) * 1024 + cc) = w1;
        }
    }

    // ---- PV for both tiles; V loaded once (batch 1 issued over batch-0 MFMAs)
    f32x4 cacc0[4], cacc1[4];
#pragma unroll
    for (int f2 = 0; f2 < 4; ++f2) {
        cacc0[f2] = (f32x4){0.f, 0.f, 0.f, 0.f};
        cacc1[f2] = (f32x4){0.f, 0.f, 0.f, 0.f};
    }
    bf16x8 vf1[4][4];
#pragma unroll
    for (int ks = 0; ks < 4; ++ks)
#pragma unroll
        for (int f2 = 0; f2 < 4; ++f2)
            vf1[ks][f2] = *reinterpret_cast<const bf16x8*>(vpb + (4 + ks) * 2048 + f2 * 512);

#pragma unroll
    for (int ks = 0; ks < 4; ++ks) {
        const int po = lr * 512 + ((ks * 64 + lg * 16) ^ myswz);
        bf16x8 pa0 = *reinterpret_cast<const bf16x8*>(tw + po);
        bf16x8 pa1 = *reinterpret_cast<const bf16x8*>(tw + 8192 + po);
#pragma unroll
        for (int f2 = 0; f2 < 4; ++f2) {
            cacc0[f2] = MFMA16(pa0, vf0[ks][f2], cacc0[f2]);
            cacc1[f2] = MFMA16(pa1, vf0[ks][f2], cacc1[f2]);
        }
    }
#pragma unroll
    for (int ks = 4; ks < 8; ++ks) {
        const int po = lr * 512 + ((ks * 64 + lg * 16) ^ myswz);
        bf16x8 pa0 = *reinterpret_cast<const bf16x8*>(tw + po);
        bf16x8 pa1 = *reinterpret_cast<const bf16x8*>(tw + 8192 + po);
#pragma unroll
        for (int f2 = 0; f2 < 4; ++f2) {
            cacc0[f2] = MFMA16(pa0, vf1[ks - 4][f2], cacc0[f2]);
            cacc1[f2] = MFMA16(pa1, vf1[ks - 4][f2], cacc1[f2]);
        }
    }

    // ---- cross-wave ctx reduce: cred[2][16][64] f32 in own region (P dead)
    {
        float* credw = reinterpret_cast<float*>(tw);
#pragma unroll
        for (int f2 = 0; f2 < 4; ++f2)
#pragma unroll
            for (int r = 0; r < 4; ++r) {
                credw[(lg * 4 + r) * 64 + f2 * 16 + lr] = cacc0[f2][r];
                credw[1024 + (lg * 4 + r) * 64 + f2 * 16 + lr] = cacc1[f2][r];
            }
    }
    __syncthreads();
    const int row_l = wave * 4 + lg;
    const int dk0 = lr * 4;
#pragma unroll
    for (int t = 0; t < 2; ++t) {
        f32x4 s0 = *reinterpret_cast<const f32x4*>(
            reinterpret_cast<const float*>(&wlds4[0][0]) + t * 1024 + row_l * 64 + dk0);
        f32x4 s1 = *reinterpret_cast<const f32x4*>(
            reinterpret_cast<const float*>(&wlds4[1][0]) + t * 1024 + row_l * 64 + dk0);
        f32x4 s2 = *reinterpret_cast<const f32x4*>(
            reinterpret_cast<const float*>(&wlds4[2][0]) + t * 1024 + row_l * 64 + dk0);
        f32x4 s3 = *reinterpret_cast<const f32x4*>(
            reinterpret_cast<const float*>(&wlds4[3][0]) + t * 1024 + row_l * 64 + dk0);
        f32x4 st = (s0 + s1) + (s2 + s3);
        bf16x4 o4 = { (bf16_t)st[0], (bf16_t)st[1], (bf16_t)st[2], (bf16_t)st[3] };
        *reinterpret_cast<bf16x4*>(
            &ctxb[(size_t)(b * 1024 + m0 + t * 16 + row_l) * 1024 + h * 64 + dk0]) = o4;
    }
}

// ---------------------------------------------------------------------- launcher
extern "C" void kernel_launch(void* const* d_in, const int* in_sizes, int n_in,
                              void* d_out, int out_size, void* d_ws, size_t ws_size,
                              hipStream_t stream) {
    const float* x    = (const float*)d_in[0];
    const float* bias = (const float*)d_in[1];
    const float* Wq   = (const float*)d_in[2];
    const float* Wk   = (const float*)d_in[3];
    const float* Wv   = (const float*)d_in[4];
    const float* Wo   = (const float*)d_in[5];
    float* out  = (float*)d_out;
    float* attn = out + (size_t)4 * 1024 * 1024;

    char* ws = (char*)d_ws;
    bf16_t* xb   = (bf16_t*)(ws);                      //  8 MB [4096,1024]
    bf16_t* wT   = (bf16_t*)(ws + ((size_t)8 << 20));  //  8 MB 4x [1024,1024] transposed
    bf16_t* qhp  = (bf16_t*)(ws + ((size_t)16 << 20)); //  8 MB Q/8 packed half-planes
    bf16_t* khp  = (bf16_t*)(ws + ((size_t)24 << 20)); //  8 MB K packed half-planes
    bf16_t* vp   = (bf16_t*)(ws + ((size_t)32 << 20)); //  8 MB V packed k-tiles
    bf16_t* ctxb = (bf16_t*)(ws + ((size_t)40 << 20)); //  8 MB ctx [B,S,D]
    bf16_t* woT = wT + ((size_t)3 << 20);

    cast_f32_bf16<<<dim3(4096), dim3(256), 0, stream>>>(x, xb, 1024 * 1024);
    transpose_cast_w<<<dim3(32, 32, 4), dim3(32, 32), 0, stream>>>(Wq, Wk, Wv, Wo, wT);

    gemm_qkv<<<dim3(32, 8, 3), dim3(256), 0, stream>>>(xb, wT, qhp, khp, vp);

    fused_attn<<<dim3(2048), dim3(256), 0, stream>>>(qhp, khp, vp, bias, attn, ctxb);

    gemm_out<<<dim3(32, 8), dim3(256), 0, stream>>>(ctxb, woT, out);
}

// Round 14
// 170.922 us; speedup vs baseline: 1.0728x; 1.0728x over previous
//
#include <hip/hip_runtime.h>
#include <hip/hip_bf16.h>

// MHA forward: B=4, S=1024, D=1024, H=16, DK=64
// outputs: out [4,1024,1024] f32, attn [4,16,1024,1024] f32 (concat in d_out)
//
// Packed operand layouts for the fused kernel (all bf16):
//   qhp/khp: [bh][half=dk/32][s][32]   -> frag loads 1KB contiguous
//   vp:      [bh][kb=s/32][dk][32]     -> PV frag loads 1KB contiguous

typedef __bf16 bf16_t;
typedef __bf16 bf16x4 __attribute__((ext_vector_type(4)));
typedef __bf16 bf16x8 __attribute__((ext_vector_type(8)));
typedef float f32x4 __attribute__((ext_vector_type(4)));

#define MFMA16(a, b, c) __builtin_amdgcn_mfma_f32_16x16x32_bf16(a, b, c, 0, 0, 0)

// ----------------------------------------- prep: transpose-cast W (z<4) + cast x (z=4)
__global__ __launch_bounds__(256) void prep(const float* __restrict__ x,
                                            const float* __restrict__ w0,
                                            const float* __restrict__ w1,
                                            const float* __restrict__ w2,
                                            const float* __restrict__ w3,
                                            bf16_t* __restrict__ xb,
                                            bf16_t* __restrict__ wt) {
    __shared__ float tile[32][33];
    const int tid = threadIdx.x;
    if (blockIdx.z == 4) {
        // cast 4M f32 -> bf16: 1024 blocks x 256 threads x 4 float4
        const int bid = blockIdx.y * 32 + blockIdx.x;
        const int base = bid * 1024 + tid;
#pragma unroll
        for (int k = 0; k < 4; ++k) {
            const int i = base + k * 256;
            float4 v = reinterpret_cast<const float4*>(x)[i];
            bf16x4 o = { (bf16_t)v.x, (bf16_t)v.y, (bf16_t)v.z, (bf16_t)v.w };
            reinterpret_cast<bf16x4*>(xb)[i] = o;
        }
        return;
    }
    const float* src = (blockIdx.z == 0) ? w0 : (blockIdx.z == 1) ? w1
                     : (blockIdx.z == 2) ? w2 : w3;
    bf16_t* dst = wt + (size_t)blockIdx.z * 1024 * 1024;
    const int r0 = blockIdx.y * 32, c0 = blockIdx.x * 32;
    const int tx = tid & 31, ty = tid >> 5;   // 32 x 8
#pragma unroll
    for (int k = 0; k < 4; ++k)
        tile[ty + k * 8][tx] = src[(size_t)(r0 + ty + k * 8) * 1024 + c0 + tx];
    __syncthreads();
#pragma unroll
    for (int k = 0; k < 4; ++k)
        dst[(size_t)(c0 + ty + k * 8) * 1024 + r0 + tx] = (bf16_t)tile[tx][ty + k * 8];
}

// ------------------------------------------------- GEMM core (128x128 tile, BK=64)
// (round-12 body — reg-staged, 16 K-steps, swizzle slot' = slot ^ (row&7))
#define GEMM_BODY(A, BT)                                                                 \
    __shared__ bf16_t As[128 * 64];                                                      \
    __shared__ bf16_t Bs[128 * 64];                                                      \
    const int tid = threadIdx.x;                                                         \
    const int lane = tid & 63, wave = tid >> 6;                                          \
    const int lr = lane & 15, lg = lane >> 4;                                            \
    const int m_base = blockIdx.x * 128, n_base = blockIdx.y * 128;                      \
    const int wm = (wave >> 1) * 64, wn = (wave & 1) * 64;                               \
    int soff_[4];                                                                        \
    const bf16_t* aptr_[4];                                                              \
    const bf16_t* bptr_[4];                                                              \
    _Pragma("unroll") for (int i = 0; i < 4; ++i) {                                      \
        const int g = i * 256 + tid;                                                     \
        const int r = g >> 3, s = g & 7;                                                 \
        soff_[i] = r * 64 + ((s ^ (r & 7)) * 8);                                         \
        aptr_[i] = (A) + (size_t)(m_base + r) * 1024 + s * 8;                            \
        bptr_[i] = (BT) + (size_t)(n_base + r) * 1024 + s * 8;                           \
    }                                                                                    \
    bf16x8 ra_[4], rb_[4];                                                               \
    _Pragma("unroll") for (int i = 0; i < 4; ++i) {                                      \
        ra_[i] = *reinterpret_cast<const bf16x8*>(aptr_[i]);                             \
        rb_[i] = *reinterpret_cast<const bf16x8*>(bptr_[i]);                             \
    }                                                                                    \
    f32x4 acc[4][4] = {};                                                                \
    for (int kb = 64; kb <= 1024; kb += 64) {                                            \
        __syncthreads();                                                                 \
        _Pragma("unroll") for (int i = 0; i < 4; ++i) {                                  \
            *reinterpret_cast<bf16x8*>(&As[soff_[i]]) = ra_[i];                          \
            *reinterpret_cast<bf16x8*>(&Bs[soff_[i]]) = rb_[i];                          \
        }                                                                                \
        if (kb < 1024) {                                                                 \
            _Pragma("unroll") for (int i = 0; i < 4; ++i) {                              \
                ra_[i] = *reinterpret_cast<const bf16x8*>(aptr_[i] + kb);                \
                rb_[i] = *reinterpret_cast<const bf16x8*>(bptr_[i] + kb);                \
            }                                                                            \
        }                                                                                \
        __syncthreads();                                                                 \
        _Pragma("unroll") for (int h = 0; h < 2; ++h) {                                  \
            bf16x8 af[4], bfr[4];                                                        \
            _Pragma("unroll") for (int i = 0; i < 4; ++i) {                              \
                const int row = wm + i * 16 + lr;                                        \
                af[i] = *reinterpret_cast<const bf16x8*>(                                \
                    &As[row * 64 + (((h * 4 + lg) ^ (row & 7)) * 8)]);                   \
            }                                                                            \
            _Pragma("unroll") for (int j = 0; j < 4; ++j) {                              \
                const int row = wn + j * 16 + lr;                                        \
                bfr[j] = *reinterpret_cast<const bf16x8*>(                               \
                    &Bs[row * 64 + (((h * 4 + lg) ^ (row & 7)) * 8)]);                   \
            }                                                                            \
            _Pragma("unroll") for (int i = 0; i < 4; ++i)                                \
                _Pragma("unroll") for (int j = 0; j < 4; ++j)                            \
                    acc[i][j] = MFMA16(af[i], bfr[j], acc[i][j]);                        \
        }                                                                                \
    }

// ---------------------------------------------------- QKV projections, one launch
// blockIdx.z: 0 = Q -> qhp (x0.125), 1 = K -> khp, 2 = V -> vp
__global__ __launch_bounds__(256, 3) void gemm_qkv(const bf16_t* __restrict__ A,
                                                   const bf16_t* __restrict__ wT,
                                                   bf16_t* __restrict__ qhp,
                                                   bf16_t* __restrict__ khp,
                                                   bf16_t* __restrict__ vp) {
    const int z = blockIdx.z;
    const bf16_t* BT = wT + ((size_t)z << 20);
    GEMM_BODY(A, BT)
    bf16_t* dst = (z == 0) ? qhp : (z == 1) ? khp : vp;
    const float scale = (z == 0) ? 0.125f : 1.0f;
#pragma unroll
    for (int i = 0; i < 4; ++i)
#pragma unroll
        for (int j = 0; j < 4; ++j)
#pragma unroll
            for (int r = 0; r < 4; ++r) {
                const int row = m_base + wm + i * 16 + lg * 4 + r;
                const int col = n_base + wn + j * 16 + lr;
                const float v = acc[i][j][r] * scale;
                const int b = row >> 10, s = row & 1023;
                const int h = col >> 6, d = col & 63;
                const size_t bh16 = (size_t)(b * 16 + h) << 16;
                if (z == 2)   // vp[bh][s/32][d][s%32]
                    dst[bh16 + ((s >> 5) << 11) + d * 32 + (s & 31)] = (bf16_t)v;
                else          // qhp/khp[bh][d/32][s][d%32]
                    dst[bh16 + ((d >> 5) << 15) + s * 32 + (d & 31)] = (bf16_t)v;
            }
}

// --------------------------- output projection: 64x128 tile -> 512 blocks (2/CU)
// gemm_out at 128x128 gave 256 blocks = 1 block/CU: barrier/stage phases fully
// exposed. 64x128 (acc[2][4], As 8KB + Bs 16KB) doubles co-residency.
__global__ __launch_bounds__(256, 2) void gemm_out(const bf16_t* __restrict__ A,
                                                   const bf16_t* __restrict__ BT,
                                                   float* __restrict__ out) {
    __shared__ bf16_t As[64 * 64];
    __shared__ bf16_t Bs[128 * 64];
    const int tid = threadIdx.x;
    const int lane = tid & 63, wave = tid >> 6;
    const int lr = lane & 15, lg = lane >> 4;
    const int m_base = blockIdx.x * 64, n_base = blockIdx.y * 128;
    const int wm = (wave >> 1) * 32, wn = (wave & 1) * 64;

    int asoff[2];
    const bf16_t* aptr[2];
#pragma unroll
    for (int i = 0; i < 2; ++i) {
        const int g = i * 256 + tid;          // 512 chunks of As
        const int r = g >> 3, s = g & 7;
        asoff[i] = r * 64 + ((s ^ (r & 7)) * 8);
        aptr[i] = A + (size_t)(m_base + r) * 1024 + s * 8;
    }
    int bsoff[4];
    const bf16_t* bptr[4];
#pragma unroll
    for (int i = 0; i < 4; ++i) {
        const int g = i * 256 + tid;          // 1024 chunks of Bs
        const int r = g >> 3, s = g & 7;
        bsoff[i] = r * 64 + ((s ^ (r & 7)) * 8);
        bptr[i] = BT + (size_t)(n_base + r) * 1024 + s * 8;
    }
    bf16x8 ra[2], rb[4];
#pragma unroll
    for (int i = 0; i < 2; ++i) ra[i] = *reinterpret_cast<const bf16x8*>(aptr[i]);
#pragma unroll
    for (int i = 0; i < 4; ++i) rb[i] = *reinterpret_cast<const bf16x8*>(bptr[i]);

    f32x4 acc[2][4] = {};
    for (int kb = 64; kb <= 1024; kb += 64) {
        __syncthreads();
#pragma unroll
        for (int i = 0; i < 2; ++i) *reinterpret_cast<bf16x8*>(&As[asoff[i]]) = ra[i];
#pragma unroll
        for (int i = 0; i < 4; ++i) *reinterpret_cast<bf16x8*>(&Bs[bsoff[i]]) = rb[i];
        if (kb < 1024) {
#pragma unroll
            for (int i = 0; i < 2; ++i) ra[i] = *reinterpret_cast<const bf16x8*>(aptr[i] + kb);
#pragma unroll
            for (int i = 0; i < 4; ++i) rb[i] = *reinterpret_cast<const bf16x8*>(bptr[i] + kb);
        }
        __syncthreads();
#pragma unroll
        for (int h = 0; h < 2; ++h) {
            bf16x8 af[2], bfr[4];
#pragma unroll
            for (int i = 0; i < 2; ++i) {
                const int row = wm + i * 16 + lr;
                af[i] = *reinterpret_cast<const bf16x8*>(
                    &As[row * 64 + (((h * 4 + lg) ^ (row & 7)) * 8)]);
            }
#pragma unroll
            for (int j = 0; j < 4; ++j) {
                const int row = wn + j * 16 + lr;
                bfr[j] = *reinterpret_cast<const bf16x8*>(
                    &Bs[row * 64 + (((h * 4 + lg) ^ (row & 7)) * 8)]);
            }
#pragma unroll
            for (int i = 0; i < 2; ++i)
#pragma unroll
                for (int j = 0; j < 4; ++j)
                    acc[i][j] = MFMA16(af[i], bfr[j], acc[i][j]);
        }
    }
#pragma unroll
    for (int i = 0; i < 2; ++i)
#pragma unroll
        for (int j = 0; j < 4; ++j)
#pragma unroll
            for (int r = 0; r < 4; ++r) {
                const int row = m_base + wm + i * 16 + lg * 4 + r;
                const int col = n_base + wn + j * 16 + lr;
                out[(size_t)row * 1024 + col] = acc[i][j][r];
            }
}

// --------------------------------------- fused scores+bias+softmax+attn-write+PV
// (unchanged from round 11 — 2-q-tile, K/V loaded once, segment-coalesced I/O)
__global__ __launch_bounds__(256, 2) void fused_attn(const bf16_t* __restrict__ qhp,
                                                     const bf16_t* __restrict__ khp,
                                                     const bf16_t* __restrict__ vp,
                                                     const float* __restrict__ bias,
                                                     float* __restrict__ attn,
                                                     bf16_t* __restrict__ ctxb) {
    __shared__ f32x4 wlds4[4][1024];        // 65536 B: per-wave 16KB region
    __shared__ float smaxp[128];            // [tile][wave*16+q]
    __shared__ float ssump[128];
    const int lane = threadIdx.x & 63;
    const int wave = threadIdx.x >> 6;
    const int lr = lane & 15, lg = lane >> 4;

    // decode 2048 blocks: g&7 = xcd slot; per-xcd: b fastest, qt, then h-ext
    const int g = blockIdx.x;
    const int j = g >> 3;                   // 0..255
    const int h = (g & 7) + 8 * (j >> 7);   // 0..15
    const int qt = (j >> 2) & 31;           // 32-row q-tile
    const int b = j & 3;
    const int bh = b * 16 + h;
    const int m0 = qt * 32;                 // tile0: m0..+15, tile1: m0+16..+31

    // Q B-frags for both tiles
    const bf16_t* qbase = qhp + ((size_t)bh << 16);
    const bf16x8 aqA0 = *reinterpret_cast<const bf16x8*>(qbase + (m0 + lr) * 32 + lg * 8);
    const bf16x8 aqA1 = *reinterpret_cast<const bf16x8*>(qbase + 32768 + (m0 + lr) * 32 + lg * 8);
    const bf16x8 aqB0 = *reinterpret_cast<const bf16x8*>(qbase + (m0 + 16 + lr) * 32 + lg * 8);
    const bf16x8 aqB1 = *reinterpret_cast<const bf16x8*>(qbase + 32768 + (m0 + 16 + lr) * 32 + lg * 8);

    const int c0 = wave * 256;              // this wave's k-col slice
    const bf16_t* kp0 = khp + ((size_t)bh << 16) + (size_t)(c0 + lr) * 32 + lg * 8;

    char* tw = reinterpret_cast<char*>(&wlds4[wave][0]);
    const int myswz = (lr & 7) << 4;

    // ---- bias tile0 -> LDS (permuted global col, linear LDS dest = swizzled tile)
    const float* bb0 = bias + ((size_t)h << 20) + (size_t)m0 * 1024 + c0;
#pragma unroll
    for (int i = 0; i < 16; ++i) {
        const int co = (lane * 4) ^ ((i & 7) * 4);
        f32x4 bv = *reinterpret_cast<const f32x4*>(bb0 + (size_t)i * 1024 + co);
        *reinterpret_cast<f32x4*>(tw + i * 1024 + lane * 16) = bv;
    }
    f32x4 acc0[16];
#pragma unroll
    for (int f = 0; f < 16; ++f)
        acc0[f] = *reinterpret_cast<const f32x4*>(tw + lr * 1024 + ((f * 64 + lg * 16) ^ myswz));

    // ---- bias tile1 -> LDS (reuse region), init acc1
    const float* bb1 = bb0 + 16 * 1024;
#pragma unroll
    for (int i = 0; i < 16; ++i) {
        const int co = (lane * 4) ^ ((i & 7) * 4);
        f32x4 bv = *reinterpret_cast<const f32x4*>(bb1 + (size_t)i * 1024 + co);
        *reinterpret_cast<f32x4*>(tw + i * 1024 + lane * 16) = bv;
    }
    f32x4 acc1[16];
#pragma unroll
    for (int f = 0; f < 16; ++f)
        acc1[f] = *reinterpret_cast<const f32x4*>(tw + lr * 1024 + ((f * 64 + lg * 16) ^ myswz));

    // ---- QK^T (swapped) for both tiles; K in 4 transient batches of 8 frags
#pragma unroll
    for (int half = 0; half < 2; ++half) {
        const bf16x8 aqA = half ? aqA1 : aqA0;
        const bf16x8 aqB = half ? aqB1 : aqB0;
#pragma unroll
        for (int bt = 0; bt < 2; ++bt) {
            bf16x8 kf[8];
#pragma unroll
            for (int u = 0; u < 8; ++u)
                kf[u] = *reinterpret_cast<const bf16x8*>(
                    kp0 + half * 32768 + (bt * 8 + u) * 512);
#pragma unroll
            for (int u = 0; u < 8; ++u) {
                acc0[bt * 8 + u] = MFMA16(kf[u], aqA, acc0[bt * 8 + u]);
                acc1[bt * 8 + u] = MFMA16(kf[u], aqB, acc1[bt * 8 + u]);
            }
        }
    }

    // ---- row max (both tiles): in-lane over 64 + shuffle xor16/32 + LDS
    f32x4 m40 = acc0[0], m41 = acc1[0];
#pragma unroll
    for (int f = 1; f < 16; ++f) {
#pragma unroll
        for (int r = 0; r < 4; ++r) {
            m40[r] = fmaxf(m40[r], acc0[f][r]);
            m41[r] = fmaxf(m41[r], acc1[f][r]);
        }
    }
    float mx0 = fmaxf(fmaxf(m40[0], m40[1]), fmaxf(m40[2], m40[3]));
    float mx1 = fmaxf(fmaxf(m41[0], m41[1]), fmaxf(m41[2], m41[3]));
    mx0 = fmaxf(mx0, __shfl_xor(mx0, 16));
    mx0 = fmaxf(mx0, __shfl_xor(mx0, 32));
    mx1 = fmaxf(mx1, __shfl_xor(mx1, 16));
    mx1 = fmaxf(mx1, __shfl_xor(mx1, 32));
    if (lane < 16) {
        smaxp[wave * 16 + lr] = mx0;
        smaxp[64 + wave * 16 + lr] = mx1;
    }
    __syncthreads();
    const float gm0 = fmaxf(fmaxf(smaxp[lr], smaxp[16 + lr]),
                            fmaxf(smaxp[32 + lr], smaxp[48 + lr]));
    const float gm1 = fmaxf(fmaxf(smaxp[64 + lr], smaxp[80 + lr]),
                            fmaxf(smaxp[96 + lr], smaxp[112 + lr]));

    // ---- exp once + row sums (both tiles)
    f32x4 s40 = {0.f, 0.f, 0.f, 0.f}, s41 = {0.f, 0.f, 0.f, 0.f};
#pragma unroll
    for (int f = 0; f < 16; ++f) {
#pragma unroll
        for (int r = 0; r < 4; ++r) {
            const float e0 = __expf(acc0[f][r] - gm0);
            const float e1 = __expf(acc1[f][r] - gm1);
            acc0[f][r] = e0;
            acc1[f][r] = e1;
            s40[r] += e0;
            s41[r] += e1;
        }
    }
    float sm0 = (s40[0] + s40[1]) + (s40[2] + s40[3]);
    float sm1 = (s41[0] + s41[1]) + (s41[2] + s41[3]);
    sm0 += __shfl_xor(sm0, 16);
    sm0 += __shfl_xor(sm0, 32);
    sm1 += __shfl_xor(sm1, 16);
    sm1 += __shfl_xor(sm1, 32);
    if (lane < 16) {
        ssump[wave * 16 + lr] = sm0;
        ssump[64 + wave * 16 + lr] = sm1;
    }
    __syncthreads();
    const float invl0 = 1.0f / (ssump[lr] + ssump[16 + lr] + ssump[32 + lr] + ssump[48 + lr]);
    const float invl1 = 1.0f / (ssump[64 + lr] + ssump[80 + lr] + ssump[96 + lr] + ssump[112 + lr]);

    // ---- issue V batch 0 early (shared by both tiles' PV)
    const bf16_t* vpb = vp + ((size_t)bh << 16) + (size_t)(wave * 8) * 2048 + lr * 32 + lg * 8;
    bf16x8 vf0[4][4];
#pragma unroll
    for (int ks = 0; ks < 4; ++ks)
#pragma unroll
        for (int f2 = 0; f2 < 4; ++f2)
            vf0[ks][f2] = *reinterpret_cast<const bf16x8*>(vpb + ks * 2048 + f2 * 512);

    // ---- normalize -> P tiles (bf16, frag-order swizzled): P0 @ 0, P1 @ 8192
#pragma unroll
    for (int f = 0; f < 16; ++f) {
        f32x4 v0 = acc0[f], v1 = acc1[f];
#pragma unroll
        for (int r = 0; r < 4; ++r) { v0[r] *= invl0; v1[r] *= invl1; }
        bf16x4 p0 = { (bf16_t)v0[0], (bf16_t)v0[1], (bf16_t)v0[2], (bf16_t)v0[3] };
        bf16x4 p1 = { (bf16_t)v1[0], (bf16_t)v1[1], (bf16_t)v1[2], (bf16_t)v1[3] };
        const int ro = lr * 512 + ((f * 32 + lg * 8) ^ myswz);
        *reinterpret_cast<bf16x4*>(tw + ro) = p0;
        *reinterpret_cast<bf16x4*>(tw + 8192 + ro) = p1;
    }

    // ---- attn stores from P tiles: linear LDS b64 read -> cvt f32 -> permuted
    //      global col cc = (lane*4)^((i&7)*8); footprint 1KB contiguous per instr
    {
        float* obase = attn + ((size_t)bh << 20) + (size_t)m0 * 1024 + c0;
#pragma unroll
        for (int i = 0; i < 16; ++i) {
            const int cc = (lane * 4) ^ ((i & 7) * 8);
            bf16x4 q0 = *reinterpret_cast<const bf16x4*>(tw + i * 512 + lane * 8);
            bf16x4 q1 = *reinterpret_cast<const bf16x4*>(tw + 8192 + i * 512 + lane * 8);
            f32x4 w0 = { (float)q0[0], (float)q0[1], (float)q0[2], (float)q0[3] };
            f32x4 w1 = { (float)q1[0], (float)q1[1], (float)q1[2], (float)q1[3] };
            *reinterpret_cast<f32x4*>(obase + (size_t)i * 1024 + cc) = w0;
            *reinterpret_cast<f32x4*>(obase + (size_t)(16 + i) * 1024 + cc) = w1;
        }
    }

    // ---- PV for both tiles; V loaded once (batch 1 issued over batch-0 MFMAs)
    f32x4 cacc0[4], cacc1[4];
#pragma unroll
    for (int f2 = 0; f2 < 4; ++f2) {
        cacc0[f2] = (f32x4){0.f, 0.f, 0.f, 0.f};
        cacc1[f2] = (f32x4){0.f, 0.f, 0.f, 0.f};
    }
    bf16x8 vf1[4][4];
#pragma unroll
    for (int ks = 0; ks < 4; ++ks)
#pragma unroll
        for (int f2 = 0; f2 < 4; ++f2)
            vf1[ks][f2] = *reinterpret_cast<const bf16x8*>(vpb + (4 + ks) * 2048 + f2 * 512);

#pragma unroll
    for (int ks = 0; ks < 4; ++ks) {
        const int po = lr * 512 + ((ks * 64 + lg * 16) ^ myswz);
        bf16x8 pa0 = *reinterpret_cast<const bf16x8*>(tw + po);
        bf16x8 pa1 = *reinterpret_cast<const bf16x8*>(tw + 8192 + po);
#pragma unroll
        for (int f2 = 0; f2 < 4; ++f2) {
            cacc0[f2] = MFMA16(pa0, vf0[ks][f2], cacc0[f2]);
            cacc1[f2] = MFMA16(pa1, vf0[ks][f2], cacc1[f2]);
        }
    }
#pragma unroll
    for (int ks = 4; ks < 8; ++ks) {
        const int po = lr * 512 + ((ks * 64 + lg * 16) ^ myswz);
        bf16x8 pa0 = *reinterpret_cast<const bf16x8*>(tw + po);
        bf16x8 pa1 = *reinterpret_cast<const bf16x8*>(tw + 8192 + po);
#pragma unroll
        for (int f2 = 0; f2 < 4; ++f2) {
            cacc0[f2] = MFMA16(pa0, vf1[ks - 4][f2], cacc0[f2]);
            cacc1[f2] = MFMA16(pa1, vf1[ks - 4][f2], cacc1[f2]);
        }
    }

    // ---- cross-wave ctx reduce: cred[2][16][64] f32 in own region (P dead)
    {
        float* credw = reinterpret_cast<float*>(tw);
#pragma unroll
        for (int f2 = 0; f2 < 4; ++f2)
#pragma unroll
            for (int r = 0; r < 4; ++r) {
                credw[(lg * 4 + r) * 64 + f2 * 16 + lr] = cacc0[f2][r];
                credw[1024 + (lg * 4 + r) * 64 + f2 * 16 + lr] = cacc1[f2][r];
            }
    }
    __syncthreads();
    const int row_l = wave * 4 + lg;
    const int dk0 = lr * 4;
#pragma unroll
    for (int t = 0; t < 2; ++t) {
        f32x4 s0 = *reinterpret_cast<const f32x4*>(
            reinterpret_cast<const float*>(&wlds4[0][0]) + t * 1024 + row_l * 64 + dk0);
        f32x4 s1 = *reinterpret_cast<const f32x4*>(
            reinterpret_cast<const float*>(&wlds4[1][0]) + t * 1024 + row_l * 64 + dk0);
        f32x4 s2 = *reinterpret_cast<const f32x4*>(
            reinterpret_cast<const float*>(&wlds4[2][0]) + t * 1024 + row_l * 64 + dk0);
        f32x4 s3 = *reinterpret_cast<const f32x4*>(
            reinterpret_cast<const float*>(&wlds4[3][0]) + t * 1024 + row_l * 64 + dk0);
        f32x4 st = (s0 + s1) + (s2 + s3);
        bf16x4 o4 = { (bf16_t)st[0], (bf16_t)st[1], (bf16_t)st[2], (bf16_t)st[3] };
        *reinterpret_cast<bf16x4*>(
            &ctxb[(size_t)(b * 1024 + m0 + t * 16 + row_l) * 1024 + h * 64 + dk0]) = o4;
    }
}

// ---------------------------------------------------------------------- launcher
extern "C" void kernel_launch(void* const* d_in, const int* in_sizes, int n_in,
                              void* d_out, int out_size, void* d_ws, size_t ws_size,
                              hipStream_t stream) {
    const float* x    = (const float*)d_in[0];
    const float* bias = (const float*)d_in[1];
    const float* Wq   = (const float*)d_in[2];
    const float* Wk   = (const float*)d_in[3];
    const float* Wv   = (const float*)d_in[4];
    const float* Wo   = (const float*)d_in[5];
    float* out  = (float*)d_out;
    float* attn = out + (size_t)4 * 1024 * 1024;

    char* ws = (char*)d_ws;
    bf16_t* xb   = (bf16_t*)(ws);                      //  8 MB [4096,1024]
    bf16_t* wT   = (bf16_t*)(ws + ((size_t)8 << 20));  //  8 MB 4x [1024,1024] transposed
    bf16_t* qhp  = (bf16_t*)(ws + ((size_t)16 << 20)); //  8 MB Q/8 packed half-planes
    bf16_t* khp  = (bf16_t*)(ws + ((size_t)24 << 20)); //  8 MB K packed half-planes
    bf16_t* vp   = (bf16_t*)(ws + ((size_t)32 << 20)); //  8 MB V packed k-tiles
    bf16_t* ctxb = (bf16_t*)(ws + ((size_t)40 << 20)); //  8 MB ctx [B,S,D]
    bf16_t* woT = wT + ((size_t)3 << 20);

    prep<<<dim3(32, 32, 5), dim3(256), 0, stream>>>(x, Wq, Wk, Wv, Wo, xb, wT);

    gemm_qkv<<<dim3(32, 8, 3), dim3(256), 0, stream>>>(xb, wT, qhp, khp, vp);

    fused_attn<<<dim3(2048), dim3(256), 0, stream>>>(qhp, khp, vp, bias, attn, ctxb);

    gemm_out<<<dim3(64, 8), dim3(256), 0, stream>>>(ctxb, woT, out);
}